// Round 1
// baseline (1126.591 us; speedup 1.0000x reference)
//
#include <hip/hip_runtime.h>
#include <hip/hip_bf16.h>

// Multi-LoRA fused: out[b,n,o] = (1/64) * sum_r ( sum_i x[b,n,i]*B[aid,r,i] ) * A[aid,o,r]
// x: [16,2048,4096] f32, ids: [16] int, A: [64,4096,64] f32, B: [64,64,4096] f32
// out: [16,2048,4096] f32

typedef __bf16 bf16x8 __attribute__((ext_vector_type(8)));
typedef float  f32x4  __attribute__((ext_vector_type(4)));

#define N_BATCH 16
#define SEQLEN  2048
#define D_IN    4096
#define D_OUT   4096
#define RNK     64
#define TN      64     // rows (n) per block
#define BK      128    // K chunk staged in LDS
#define BKP     136    // padded LDS row (bf16 elems): stride 272B -> 2-way bank alias (free)
#define BXP     72     // padded Bx LDS row: stride 144B -> 2-way alias (free)

__device__ __forceinline__ bf16x8 cvt8(f32x4 a, f32x4 b) {
    bf16x8 r;
    r[0] = (__bf16)a[0]; r[1] = (__bf16)a[1]; r[2] = (__bf16)a[2]; r[3] = (__bf16)a[3];
    r[4] = (__bf16)b[0]; r[5] = (__bf16)b[1]; r[6] = (__bf16)b[2]; r[7] = (__bf16)b[3];
    return r;
}

__global__ __launch_bounds__(256, 2) void lora_fused(
    const float* __restrict__ x, const int* __restrict__ ids,
    const float* __restrict__ A, const float* __restrict__ Bw,
    float* __restrict__ out)
{
    __shared__ __bf16 xs[TN * BKP];   // 17408 B
    __shared__ __bf16 bxs[TN * BXP];  //  9216 B

    const int tid  = threadIdx.x;
    const int wave = tid >> 6;
    const int lane = tid & 63;
    const int l15  = lane & 15;
    const int quad = lane >> 4;

    // XCD swizzle: assume round-robin blockIdx->XCD (%8). Pack each batch's 32
    // blocks onto one XCD (2 batches/XCD) so A/B stay L2-resident per XCD.
    const int blk  = blockIdx.x;
    const int slot = blk >> 3;
    const int b    = (blk & 7) * 2 + (slot >> 5);  // 0..15
    const int nt   = slot & 31;                    // 0..31

    const int aid = ids[b];
    const float* xb = x   + ((size_t)b * SEQLEN + (size_t)nt * TN) * D_IN;
    float*       ob = out + ((size_t)b * SEQLEN + (size_t)nt * TN) * D_OUT;
    const float* Aq = A  + (size_t)aid * D_OUT * RNK;
    const float* Bq = Bw + (size_t)aid * RNK * D_IN;

    f32x4 zero; zero[0] = zero[1] = zero[2] = zero[3] = 0.0f;

    // ---- Stage 1: Bx[n, r] = sum_k x[n,k] * B[r,k], wave w owns r-tile w ----
    f32x4 acc[4];  // 4 n-tiles of 16, each lane: row=quad*4+j, col(r)=16w+l15
    #pragma unroll
    for (int t = 0; t < 4; ++t) acc[t] = zero;

    const int srow = tid >> 2;   // 0..63: staging row
    const int sq   = tid & 3;    // quarter of the 128-wide K chunk
    const float* xsrc = xb + (size_t)srow * D_IN + sq * 32;
    __bf16* xdst = &xs[srow * BKP + sq * 32];
    const float* bsrc = Bq + (size_t)(wave * 16 + l15) * D_IN + quad * 8;

    for (int kb = 0; kb < D_IN / BK; ++kb) {
        __syncthreads();  // protect xs from previous iteration's readers
        const float* sp = xsrc + kb * BK;
        #pragma unroll
        for (int i = 0; i < 4; ++i) {
            f32x4 v0 = __builtin_nontemporal_load((const f32x4*)(sp + i * 8));
            f32x4 v1 = __builtin_nontemporal_load((const f32x4*)(sp + i * 8 + 4));
            *(bf16x8*)(xdst + i * 8) = cvt8(v0, v1);
        }
        __syncthreads();

        const float* bp = bsrc + kb * BK;
        #pragma unroll
        for (int s = 0; s < 4; ++s) {
            f32x4 b0 = *(const f32x4*)(bp + s * 32);
            f32x4 b1 = *(const f32x4*)(bp + s * 32 + 4);
            bf16x8 bfrag = cvt8(b0, b1);  // B[k=quad*8+j][r=16w+l15]
            #pragma unroll
            for (int t = 0; t < 4; ++t) {
                bf16x8 afrag = *(const bf16x8*)&xs[(t * 16 + l15) * BKP + s * 32 + quad * 8];
                acc[t] = __builtin_amdgcn_mfma_f32_16x16x32_bf16(afrag, bfrag, acc[t], 0, 0, 0);
            }
        }
    }

    // ---- Bx -> LDS as bf16 (fold exact 1/64 scaling here) ----
    #pragma unroll
    for (int t = 0; t < 4; ++t)
        #pragma unroll
        for (int j = 0; j < 4; ++j)
            bxs[(t * 16 + quad * 4 + j) * BXP + wave * 16 + l15] =
                (__bf16)(acc[t][j] * 0.015625f);
    __syncthreads();

    // A-operand frags for stage 2: a2[t][s] = Bx[n=16t+l15][r=s*32+quad*8+j]
    bf16x8 a2[4][2];
    #pragma unroll
    for (int t = 0; t < 4; ++t)
        #pragma unroll
        for (int s = 0; s < 2; ++s)
            a2[t][s] = *(const bf16x8*)&bxs[(t * 16 + l15) * BXP + s * 32 + quad * 8];

    // ---- Stage 2: out[n, o] = sum_r Bx[n,r] * A[o,r]; wave w owns o%256 slice ----
    for (int oc = 0; oc < 16; ++oc) {
        const int o0 = oc * 256 + wave * 64;
        bf16x8 b2[4][2];  // B2[k=r][o]: lane holds A[o=o0+16ot+l15][r=s*32+quad*8+j]
        #pragma unroll
        for (int ot = 0; ot < 4; ++ot) {
            const float* ap = Aq + (size_t)(o0 + ot * 16 + l15) * RNK + quad * 8;
            #pragma unroll
            for (int s = 0; s < 2; ++s) {
                f32x4 a0 = *(const f32x4*)(ap + s * 32);
                f32x4 a1 = *(const f32x4*)(ap + s * 32 + 4);
                b2[ot][s] = cvt8(a0, a1);
            }
        }
        f32x4 acc2[4][4];
        #pragma unroll
        for (int t = 0; t < 4; ++t)
            #pragma unroll
            for (int ot = 0; ot < 4; ++ot)
                acc2[t][ot] = zero;
        #pragma unroll
        for (int s = 0; s < 2; ++s)
            #pragma unroll
            for (int ot = 0; ot < 4; ++ot)
                #pragma unroll
                for (int t = 0; t < 4; ++t)
                    acc2[t][ot] = __builtin_amdgcn_mfma_f32_16x16x32_bf16(
                        a2[t][s], b2[ot][s], acc2[t][ot], 0, 0, 0);
        #pragma unroll
        for (int t = 0; t < 4; ++t)
            #pragma unroll
            for (int j = 0; j < 4; ++j)
                #pragma unroll
                for (int ot = 0; ot < 4; ++ot)
                    __builtin_nontemporal_store(
                        acc2[t][ot][j],
                        ob + (size_t)(t * 16 + quad * 4 + j) * D_OUT + o0 + ot * 16 + l15);
    }
}

extern "C" void kernel_launch(void* const* d_in, const int* in_sizes, int n_in,
                              void* d_out, int out_size, void* d_ws, size_t ws_size,
                              hipStream_t stream) {
    (void)in_sizes; (void)n_in; (void)d_ws; (void)ws_size; (void)out_size;
    const float* x   = (const float*)d_in[0];
    const int*   ids = (const int*)d_in[1];   // harness delivers integer inputs as int32
    const float* A   = (const float*)d_in[2];
    const float* B   = (const float*)d_in[3];
    float*       out = (float*)d_out;

    dim3 grid(512), block(256);
    hipLaunchKernelGGL(lora_fused, grid, block, 0, stream, x, ids, A, B, out);
}